// Round 1
// 10703.876 us; speedup vs baseline: 1.0472x; 1.0472x over previous
//
#include <hip/hip_runtime.h>
#include <math.h>

#define TT 4096
#define HH 1500
#define NB 250     // blocks; each owns 6 hidden units
#define NT 512     // 8 waves: 0..5 matvec (wave = unit, 4 gate rows each),
                   //          6 = x-proj + poll, 7 = poll + gates + publish
#define NREP 8     // pub replicas (reader sharding)

typedef unsigned uv4 __attribute__((ext_vector_type(4)));
typedef _Float16 h2f __attribute__((ext_vector_type(2)));
typedef _Float16 h4f __attribute__((ext_vector_type(4)));

#define ALD4(p)   __hip_atomic_load((p), __ATOMIC_RELAXED, __HIP_MEMORY_SCOPE_AGENT)
#define AST4(p,v) __hip_atomic_store((p), (v), __ATOMIC_RELAXED, __HIP_MEMORY_SCOPE_AGENT)

__device__ __forceinline__ float fast_sigmoid(float z) {
  return 1.0f / (1.0f + __expf(-z));
}
__device__ __forceinline__ float fast_tanh(float z) {
  float az = fabsf(z);
  float e  = __expf(-2.0f * az);
  float r  = (1.0f - e) / (1.0f + e);
  return copysignf(r, z);
}
// fp16 pair dot with fp32 accumulate (v_dot2_f32_f16)
__device__ __forceinline__ float dot2(unsigned wb, unsigned hb, float acc) {
#if __has_builtin(__builtin_amdgcn_fdot2)
  return __builtin_amdgcn_fdot2(__builtin_bit_cast(h2f, wb),
                                __builtin_bit_cast(h2f, hb), acc, false);
#else
  h2f w = __builtin_bit_cast(h2f, wb), h = __builtin_bit_cast(h2f, hb);
  acc = fmaf((float)w.x, (float)h.x, acc);
  return fmaf((float)w.y, (float)h.y, acc);
#endif
}

// R12: x4 bypass poll. R10/R11 diagnosis: poll storm = LLC *request-count*
// congestion (FETCH_SIZE 350MB vs 48MB of real traffic = ~300MB of dword-
// granular sc0sc1 poll loads; 250 blocks x 1536 req/iter ~ 200+ req/cy at
// the IC). Tags live in EVERY dword, so a 16B global_load_dwordx4 (sc0 sc1,
// per-dword atomicity is a HW guarantee for aligned loads) keeps detection
// granularity while cutting requests 4x: 1536 -> 384 per block-iteration.
// Pad is chunk-aligned (1500 = 4*375) -> tag guard stays chunk-uniform.
// Publisher side / tag scheme / replica layout unchanged from R11.
__device__ __forceinline__ void poll3(const unsigned* a0, const unsigned* a1,
                                      const unsigned* a2,
                                      uv4& v0, uv4& v1, uv4& v2) {
  asm volatile(
      "global_load_dwordx4 %0, %3, off sc0 sc1\n\t"
      "global_load_dwordx4 %1, %4, off sc0 sc1\n\t"
      "global_load_dwordx4 %2, %5, off sc0 sc1\n\t"
      "s_waitcnt vmcnt(0)"
      : "=&v"(v0), "=&v"(v1), "=&v"(v2)
      : "v"(a0), "v"(a1), "v"(a2)
      : "memory");
}
__device__ __forceinline__ h4f cvt4h(uv4 v) {
  h4f r;
  r.x = (_Float16)__uint_as_float(v.x);
  r.y = (_Float16)__uint_as_float(v.y);
  r.z = (_Float16)__uint_as_float(v.z);
  r.w = (_Float16)__uint_as_float(v.w);
  return r;
}

__global__
__attribute__((amdgpu_flat_work_group_size(NT, NT), amdgpu_waves_per_eu(2, 2)))
void lstm_fused(
    const float* __restrict__ x,    // (4096, 20)
    const float* __restrict__ Wih,  // (6000, 20)
    const float* __restrict__ Whh,  // (6000, 1500)
    const float* __restrict__ bih,  // (6000,)
    const float* __restrict__ bhh,  // (6000,)
    const float* __restrict__ W1,   // (1875, 1500)
    const float* __restrict__ b1,   // (1875,)
    const float* __restrict__ W2,   // (20, 1875)
    const float* __restrict__ b2,   // (20,)
    float* __restrict__ out,        // (20,)
    unsigned* __restrict__ ws)
{
  const int tid = threadIdx.x;
  const int bid = blockIdx.x;
  const int wv  = tid >> 6;   // wave 0..7
  const int ln  = tid & 63;

  // pub: [NREP][2][1536] tagged dwords; block b owns dwords 6b..6b+5 of each
  // replica/slot. hidp after.
  unsigned* pub  = ws;
  unsigned* hidp = ws + NREP * 2 * 1536;   // [1875] tagged hid values

  // weights: 24 rows (r=u*4+g) x 1536 halves (1500 + zero pad) = 73,728 B
  __shared__ __align__(16) _Float16 lds_wh[24 * 1536];
  __shared__ __align__(16) _Float16 lds_hh[1536];  // h(t) as fp16
  __shared__ __align__(16) float    lds_hf[1536];  // h(TT) fp32 for MLP
  __shared__ float lds_xp[2][24];                  // x-proj dbuf: [par][g*6+u]
  __shared__ float lds_gs[4][6];                   // gate sums: [g][u]
  float* lds_hd = (float*)lds_wh;                  // alias (block 0, post-loop)
  // total ~83.1 KB > 80 KiB -> exactly 1 block/CU (lockstep chain intact)

  // ---- stage W_hh slice into LDS, converting fp32 -> fp16 ----
  for (int hi = tid; hi < 24 * 1536; hi += NT) {
    const int r = hi / 1536, k = hi - r * 1536;
    const int u = r >> 2, g = r & 3;
    const size_t grow = (size_t)(g * HH + bid * 6 + u) * HH;
    const float v = (k < HH) ? Whh[grow + k] : 0.f;
    lds_wh[hi] = (_Float16)v;
  }

  // matvec bases (waves 0..5): 192 b128-chunks per row
  const int uu = (wv < 6) ? wv : 0;
  const uv4* wp = ((const uv4*)lds_wh) + (size_t)uu * 4 * 192;
  const uv4* hp = (const uv4*)lds_hh;

  // ---- wave 6 lanes 0..23: persistent Wih row (g=ln/6, u=ln%6) + x(0) ----
  float4 wx0, wx1, wx2, wx3, wx4;
  float4 xr0, xr1, xr2, xr3, xr4;
  float bias = 0.f;
  if (wv == 6 && ln < 24) {
    const int g = ln / 6, u = ln - g * 6;
    const int row = g * HH + bid * 6 + u;
    const float4* s = (const float4*)(Wih + row * 20);
    wx0 = s[0]; wx1 = s[1]; wx2 = s[2]; wx3 = s[3]; wx4 = s[4];
    bias = bih[row] + bhh[row];
    const float4* xx = (const float4*)x;
    xr0 = xx[0]; xr1 = xx[1]; xr2 = xx[2]; xr3 = xx[3]; xr4 = xx[4];
  }

  float c = 0.f;  // cell state: wave 7 lanes 0..5 (unit = ln)

  // init publish: h(0)=0 with tag 1 into ALL replicas, slot 0
  if (tid < 6 * NREP)
    AST4(pub + (tid / 6) * 3072 + 6 * bid + (tid % 6), 1u);

  __syncthreads();   // weights staged

  // this block's poll replica
  unsigned* myrep = pub + (bid & (NREP - 1)) * 3072;

  for (int t = 0; t < TT; ++t) {
    const int s = t & 1;
    const unsigned tag = (unsigned)((t + 1) & 15);

    // ================= P phase (pre-A) =================
    uv4 pw[12];
    if (wv < 6) {
      // prefetch ALL 12 weight b128 (48 VGPRs) — overlaps the poll below
      #pragma unroll
      for (int g = 0; g < 4; ++g) {
        #pragma unroll
        for (int m = 0; m < 3; ++m) pw[g * 3 + m] = wp[g * 192 + ln + 64 * m];
      }
    } else {
      if (wv == 6 && ln < 24) {
        // x-projection for step t (from registers, h-independent)
        float sx = bias;
        sx += wx0.x*xr0.x + wx0.y*xr0.y + wx0.z*xr0.z + wx0.w*xr0.w;
        sx += wx1.x*xr1.x + wx1.y*xr1.y + wx1.z*xr1.z + wx1.w*xr1.w;
        sx += wx2.x*xr2.x + wx2.y*xr2.y + wx2.z*xr2.z + wx2.w*xr2.w;
        sx += wx3.x*xr3.x + wx3.y*xr3.y + wx3.z*xr3.z + wx3.w*xr3.w;
        sx += wx4.x*xr4.x + wx4.y*xr4.y + wx4.z*xr4.z + wx4.w*xr4.w;
        lds_xp[s][ln] = sx;
      }
      // ---- x4 bypass tagged poll of replica bid&7 (3 req/lane/iter) ----
      const int p4 = (tid - 384) << 2;        // 0,4,...,508
      unsigned* base = myrep + s * 1536;
      uv4 v0, v1, v2;
      for (;;) {
        poll3(base + p4, base + p4 + 512, base + p4 + 1024, v0, v1, v2);
        unsigned miss = ((v0.x & 15u) ^ tag) | ((v0.y & 15u) ^ tag)
                      | ((v0.z & 15u) ^ tag) | ((v0.w & 15u) ^ tag)
                      | ((v1.x & 15u) ^ tag) | ((v1.y & 15u) ^ tag)
                      | ((v1.z & 15u) ^ tag) | ((v1.w & 15u) ^ tag);
        if (p4 + 1024 < HH)   // chunk-uniform: 1500 = 4*375
          miss |= ((v2.x & 15u) ^ tag) | ((v2.y & 15u) ^ tag)
                | ((v2.z & 15u) ^ tag) | ((v2.w & 15u) ^ tag);
        if (!__any(miss != 0u)) break;
        __builtin_amdgcn_s_sleep(1);
      }
      *(h4f*)(lds_hh + p4)       = cvt4h(v0);
      *(h4f*)(lds_hh + p4 + 512) = cvt4h(v1);
      h4f z = {(_Float16)0.f, (_Float16)0.f, (_Float16)0.f, (_Float16)0.f};
      *(h4f*)(lds_hh + p4 + 1024) = (p4 + 1024 < HH) ? cvt4h(v2) : z;
    }
    __syncthreads();   // ---- A: h(t) fp16, xp(t) staged ----

    // ================= M phase =================
    if (wv < 6) {
      uv4 hv[3];
      #pragma unroll
      for (int m = 0; m < 3; ++m) hv[m] = hp[ln + 64 * m];
      float a[4] = {0.f, 0.f, 0.f, 0.f};
      #pragma unroll
      for (int g = 0; g < 4; ++g) {
        #pragma unroll
        for (int m = 0; m < 3; ++m) {
          const uv4 q = pw[g * 3 + m], h = hv[m];
          a[g] = dot2(q.x, h.x, a[g]);
          a[g] = dot2(q.y, h.y, a[g]);
          a[g] = dot2(q.z, h.z, a[g]);
          a[g] = dot2(q.w, h.w, a[g]);
        }
      }
      // fold-select reduce: 12 swizzles + 1 ds_write
      #pragma unroll
      for (int g = 0; g < 4; ++g) {
        a[g] += __shfl_xor(a[g], 16, 64);
        a[g] += __shfl_xor(a[g], 32, 64);
      }
      const int q4 = ln >> 4;
      float v = (q4 == 0) ? a[0] : (q4 == 1) ? a[1] : (q4 == 2) ? a[2] : a[3];
      v += __shfl_xor(v, 1, 64);
      v += __shfl_xor(v, 2, 64);
      v += __shfl_xor(v, 4, 64);
      v += __shfl_xor(v, 8, 64);
      if ((ln & 15) == 0) lds_gs[q4][wv] = v;
    } else if (wv == 6 && ln < 24 && (t + 1) < TT) {
      // prefetch x(t+1) while waves 0-5 compute
      const float4* xx = (const float4*)(x + 20 * (t + 1));
      xr0 = xx[0]; xr1 = xx[1]; xr2 = xx[2]; xr3 = xx[3]; xr4 = xx[4];
    }
    __syncthreads();   // ---- B: gate sums ready ----

    // ================= G phase: wave 7 only =================
    if (wv == 7) {
      unsigned bits = 0u;
      if (ln < 6) {
        const int u = ln;
        const float zi = lds_gs[0][u] + lds_xp[s][0 + u];
        const float zf = lds_gs[1][u] + lds_xp[s][6 + u];
        const float zg = lds_gs[2][u] + lds_xp[s][12 + u];
        const float zo = lds_gs[3][u] + lds_xp[s][18 + u];
        const float ig = fast_sigmoid(zi);
        const float fg = fast_sigmoid(zf);
        const float gg = fast_tanh(zg);
        const float og = fast_sigmoid(zo);
        c = fg * c + ig * gg;
        const float hn = og * fast_tanh(c);
        bits = (__float_as_uint(hn) & ~15u) | (unsigned)((t + 2) & 15);
      }
      // broadcast 6 tagged dwords to lanes 0..47; store to all 8 replicas
      const int u6 = ln % 6;
      const unsigned myb = (unsigned)__shfl((int)bits, u6, 64);
      if (ln < 6 * NREP) {
        const int rep = ln / 6;
        AST4(pub + rep * 3072 + ((t + 1) & 1) * 1536 + 6 * bid + u6, myb);
      }
    }
  }

  // ---- final gather h(TT) fp32 into lds_hf (slot 0, tag 1) ----
  if (wv >= 6) {
    const unsigned tagf = (unsigned)((TT + 1) & 15);
    const int p4 = (tid - 384) << 2;
    unsigned* base = myrep;   // slot 0 of own replica
    uv4 v0, v1, v2;
    for (;;) {
      poll3(base + p4, base + p4 + 512, base + p4 + 1024, v0, v1, v2);
      unsigned miss = ((v0.x & 15u) ^ tagf) | ((v0.y & 15u) ^ tagf)
                    | ((v0.z & 15u) ^ tagf) | ((v0.w & 15u) ^ tagf)
                    | ((v1.x & 15u) ^ tagf) | ((v1.y & 15u) ^ tagf)
                    | ((v1.z & 15u) ^ tagf) | ((v1.w & 15u) ^ tagf);
      if (p4 + 1024 < HH)
        miss |= ((v2.x & 15u) ^ tagf) | ((v2.y & 15u) ^ tagf)
              | ((v2.z & 15u) ^ tagf) | ((v2.w & 15u) ^ tagf);
      if (!__any(miss != 0u)) break;
      __builtin_amdgcn_s_sleep(1);
    }
    float4 f0 = {__uint_as_float(v0.x), __uint_as_float(v0.y),
                 __uint_as_float(v0.z), __uint_as_float(v0.w)};
    float4 f1 = {__uint_as_float(v1.x), __uint_as_float(v1.y),
                 __uint_as_float(v1.z), __uint_as_float(v1.w)};
    float4 f2 = {__uint_as_float(v2.x), __uint_as_float(v2.y),
                 __uint_as_float(v2.z), __uint_as_float(v2.w)};
    float4 z4 = {0.f, 0.f, 0.f, 0.f};
    *(float4*)(lds_hf + p4)        = f0;
    *(float4*)(lds_hf + p4 + 512)  = f1;
    *(float4*)(lds_hf + p4 + 1024) = (p4 + 1024 < HH) ? f2 : z4;
  }
  __syncthreads();

  // ---- MLP layer 1: wave wv computes row r = bid + 250*wv ----
  {
    const float4* h4 = (const float4*)lds_hf;
    const int r = bid + 250 * wv;
    if (r < 1875) {
      const float4* wrow = (const float4*)(W1 + (size_t)r * HH);
      float ss = 0.f;
      #pragma unroll
      for (int m = 0; m < 6; ++m) {
        const int idx = ln + 64 * m;
        if (idx < 375) {
          const float4 a = wrow[idx], hv = h4[idx];
          ss += a.x*hv.x + a.y*hv.y + a.z*hv.z + a.w*hv.w;
        }
      }
      #pragma unroll
      for (int off = 32; off > 0; off >>= 1) ss += __shfl_xor(ss, off, 64);
      if (ln == 0) {
        const float vv = ss + b1[r];
        AST4(hidp + r, (__float_as_uint(vv) & ~15u) | 5u);  // tag 5 != poison 10
      }
    }
  }
  if (bid != 0) return;

  // ---- block 0: gather hid (into lds_wh alias), MLP layer 2, write out ----
  __syncthreads();
  for (int j = tid; j < 1875; j += NT) {
    unsigned bts;
    for (;;) {
      bts = ALD4(hidp + j);
      if ((bts & 15u) == 5u) break;
      __builtin_amdgcn_s_sleep(1);
    }
    lds_hd[j] = __uint_as_float(bts);
  }
  __syncthreads();

  for (int r = wv; r < 20; r += 8) {
    float ss = 0.f;
    for (int k = ln; k < 1875; k += 64)
      ss = fmaf(W2[(size_t)r * 1875 + k], lds_hd[k], ss);
    #pragma unroll
    for (int off = 32; off > 0; off >>= 1) ss += __shfl_xor(ss, off, 64);
    if (ln == 0) out[r] = ss + b2[r];
  }
}

extern "C" void kernel_launch(void* const* d_in, const int* in_sizes, int n_in,
                              void* d_out, int out_size, void* d_ws, size_t ws_size,
                              hipStream_t stream) {
  const float* x   = (const float*)d_in[0];
  const float* Wih = (const float*)d_in[1];
  const float* Whh = (const float*)d_in[2];
  const float* bih = (const float*)d_in[3];
  const float* bhh = (const float*)d_in[4];
  const float* W1  = (const float*)d_in[5];
  const float* b1  = (const float*)d_in[6];
  const float* W2  = (const float*)d_in[7];
  const float* b2  = (const float*)d_in[8];
  float* out   = (float*)d_out;
  unsigned* ws = (unsigned*)d_ws;   // uses ~106 KB (8 pub replicas + hidp)

  // 250 blocks x 512 threads, ~83 KB LDS (>80 KiB -> 1 block/CU), 250 <= 256
  // CUs: all blocks co-resident -> the tagged exchange cannot deadlock.
  hipLaunchKernelGGL(lstm_fused, dim3(NB), dim3(NT), 0, stream,
                     x, Wih, Whh, bih, bhh, W1, b1, W2, b2, out, ws);
}